// Round 19
// baseline (225.234 us; speedup 1.0000x reference)
//
#include <hip/hip_runtime.h>

typedef unsigned short u16;
typedef unsigned int u32;
typedef unsigned long long u64;
typedef __attribute__((ext_vector_type(8))) short short8;
typedef __attribute__((ext_vector_type(4))) float f32x4;

#define D_MODEL 1024
#define SEQ 2048
#define NH 16
#define DK 64
#define DFF 4096
#define NTOK 4096
#define LOG2E 1.44269504f

__device__ __forceinline__ u16 f2bf(float f) {
    unsigned x = __builtin_bit_cast(unsigned, f);
    x = x + 0x7fffu + ((x >> 16) & 1u);
    return (u16)(x >> 16);
}

__device__ __forceinline__ float bf2f(u16 v) {
    return __builtin_bit_cast(float, (u32)v << 16);
}

// bare v_exp_f32 (inputs <= 8 after defer-max; flush-to-zero ok)
__device__ __forceinline__ float fexp2(float x) {
    float r;
    asm("v_exp_f32 %0, %1" : "=v"(r) : "v"(x));
    return r;
}

__device__ __forceinline__ void gload_lds16(const void* g, void* l) {
    __builtin_amdgcn_global_load_lds(
        (__attribute__((address_space(1))) void*)g,
        (__attribute__((address_space(3))) void*)l, 16, 0, 0);
}

// ---------------- fp32 -> bf16 convert: all 7 tensors in one launch ----------------
__device__ __forceinline__ void cvt_body(const float* __restrict__ in,
                                         u16* __restrict__ out, int blk) {
    size_t i = ((size_t)blk * 256 + threadIdx.x) * 4;
    float4 v = *(const float4*)(in + i);
    out[i + 0] = f2bf(v.x);
    out[i + 1] = f2bf(v.y);
    out[i + 2] = f2bf(v.z);
    out[i + 3] = f2bf(v.w);
}

__global__ __launch_bounds__(256) void cvt_all(
    const float* __restrict__ sx, const float* __restrict__ s0,
    const float* __restrict__ s1, const float* __restrict__ s2,
    const float* __restrict__ s3, const float* __restrict__ s4,
    const float* __restrict__ s5, u16* __restrict__ dx, u16* __restrict__ d0,
    u16* __restrict__ d1, u16* __restrict__ d2, u16* __restrict__ d3,
    u16* __restrict__ d4, u16* __restrict__ d5) {
    int f = blockIdx.x;
    if (f < 4096) {
        cvt_body(sx, dx, f);
    } else if (f < 8192) {
        int which = (f - 4096) >> 10, blk = (f - 4096) & 1023;
        const float* s = which == 0 ? s0 : which == 1 ? s1 : which == 2 ? s2 : s3;
        u16* d = which == 0 ? d0 : which == 1 ? d1 : which == 2 ? d2 : d3;
        cvt_body(s, d, blk);
    } else if (f < 12288) {
        cvt_body(s4, d4, f - 8192);
    } else {
        cvt_body(s5, d5, f - 12288);
    }
}

// ---------------- shared 64x128 tile, BK=64 GEMM core (XOR-swizzled LDS) ----------------
// Single-buffered (24KB LDS -> 6 blocks/CU); occupancy provides the latency hiding.
__device__ __forceinline__ void gemm_core64(const u16* __restrict__ A,
                                            const u16* __restrict__ W, int K,
                                            int m0, int n0, int kbase, int kl,
                                            f32x4 (&acc)[2][4]) {
    __shared__ short8 As[64][8];
    __shared__ short8 Bs[128][8];
    const int tid = threadIdx.x;
    const int lane = tid & 63, w = tid >> 6;
    const int l15 = lane & 15, lg = lane >> 4;
    const int wr = (w >> 1) * 32, wc = (w & 1) * 64;
    const int psw = l15 & 7;

#pragma unroll
    for (int i = 0; i < 2; ++i)
#pragma unroll
        for (int jj = 0; jj < 4; ++jj) acc[i][jj] = (f32x4){0.f, 0.f, 0.f, 0.f};

    for (int k0 = kbase; k0 < kbase + kl; k0 += 64) {
        __syncthreads();
#pragma unroll
        for (int jj = 0; jj < 2; ++jj) {
            int idx = jj * 256 + tid;
            int r = idx >> 3, ck = idx & 7;
            gload_lds16(A + (size_t)(m0 + r) * K + k0 + ((ck ^ (r & 7)) * 8),
                        (char*)As + (jj * 256 + w * 64) * 16);
        }
#pragma unroll
        for (int jj = 0; jj < 4; ++jj) {
            int idx = jj * 256 + tid;
            int r = idx >> 3, ck = idx & 7;
            gload_lds16(W + (size_t)(n0 + r) * K + k0 + ((ck ^ (r & 7)) * 8),
                        (char*)Bs + (jj * 256 + w * 64) * 16);
        }
        __syncthreads();

#pragma unroll
        for (int kk = 0; kk < 2; ++kk) {
            short8 af[2], bf[4];
#pragma unroll
            for (int m = 0; m < 2; ++m)
                af[m] = As[wr + m * 16 + l15][(kk * 4 + lg) ^ psw];
#pragma unroll
            for (int nn = 0; nn < 4; ++nn)
                bf[nn] = Bs[wc + nn * 16 + l15][(kk * 4 + lg) ^ psw];
#pragma unroll
            for (int m = 0; m < 2; ++m)
#pragma unroll
                for (int nn = 0; nn < 4; ++nn)
                    acc[m][nn] = __builtin_amdgcn_mfma_f32_16x16x32_bf16(
                        af[m], bf[nn], acc[m][nn], 0, 0, 0);
        }
    }
}

// ---------------- k64 GEMM, bf16 out, optional split-K (Wo/W2, N=1024) ----------------
__global__ __launch_bounds__(256) void gemm_k64(
    const u16* __restrict__ A, const u16* __restrict__ W,
    const float* __restrict__ bias, u16* __restrict__ outb,
    u16* __restrict__ outb2, int M, int N, int K, int KZ) {
    const int f = blockIdx.x;
    const int xcd = f & 7, j = f >> 3;
    const int mi = j & 7, n = (j >> 3) & 7, kz = j >> 6;
    const int m0 = (xcd * 8 + mi) * 64, n0 = n * 128;
    const int kl = K / KZ, kbase = kz * kl;
    u16* out = kz ? outb2 : outb;

    f32x4 acc[2][4];
    gemm_core64(A, W, K, m0, n0, kbase, kl, acc);

    const int lane = threadIdx.x & 63, w = threadIdx.x >> 6;
    const int l15 = lane & 15, lg = lane >> 4;
    const int wr = (w >> 1) * 32, wc = (w & 1) * 64;
#pragma unroll
    for (int m = 0; m < 2; ++m)
#pragma unroll
        for (int nn = 0; nn < 4; ++nn) {
            int gn = n0 + wc + nn * 16 + l15;
            float bv = (kz == 0) ? bias[gn] : 0.f;
#pragma unroll
            for (int r = 0; r < 4; ++r) {
                int gm = m0 + wr + m * 16 + lg * 4 + r;
                out[(size_t)gm * N + gn] = f2bf(acc[m][nn][r] + bv);
            }
        }
}

// ---------------- k64 GEMM, relu bf16 out (W1, N=4096): 2048 blocks ----------------
__global__ __launch_bounds__(256) void gemm_k64_relu(
    const u16* __restrict__ A, const u16* __restrict__ W,
    const float* __restrict__ bias, u16* __restrict__ outb, int M, int N,
    int K) {
    const int f = blockIdx.x;
    const int xcd = f & 7, j = f >> 3;          // j 0..255
    const int mi = j & 7, n = j >> 3;           // n 0..31
    const int m0 = (xcd * 8 + mi) * 64, n0 = n * 128;

    f32x4 acc[2][4];
    gemm_core64(A, W, K, m0, n0, 0, K, acc);

    const int lane = threadIdx.x & 63, w = threadIdx.x >> 6;
    const int l15 = lane & 15, lg = lane >> 4;
    const int wr = (w >> 1) * 32, wc = (w & 1) * 64;
#pragma unroll
    for (int m = 0; m < 2; ++m)
#pragma unroll
        for (int nn = 0; nn < 4; ++nn) {
            int gn = n0 + wc + nn * 16 + l15;
            float bv = bias[gn];
#pragma unroll
            for (int r = 0; r < 4; ++r) {
                int gm = m0 + wr + m * 16 + lg * 4 + r;
                outb[(size_t)gm * N + gn] = f2bf(fmaxf(acc[m][nn][r] + bv, 0.f));
            }
        }
}

// ---------------- fused QKV on k64 core: 1536 blocks, m-stripe per XCD ----------------
// Q/K in [B,H,S,dk] (Q pre-scaled by 1/8*log2e); V transposed+swizzled to [B,H,dk,S].
__global__ __launch_bounds__(256) void gemm_qkv(
    const u16* __restrict__ A, const u16* __restrict__ Wq,
    const u16* __restrict__ Wk, const u16* __restrict__ Wv,
    const float* __restrict__ bq, const float* __restrict__ bk,
    const float* __restrict__ bv, u16* __restrict__ Qo, u16* __restrict__ Ko,
    u16* __restrict__ Vo) {
    const int f = blockIdx.x;
    const int xcd = f & 7, j = f >> 3;          // j 0..191
    const int mi = j & 7, q = j >> 3;           // q 0..23
    const int mat = q >> 3;
    const int m0 = (xcd * 8 + mi) * 64, n0 = (q & 7) * 128;
    const u16* W = mat == 0 ? Wq : (mat == 1 ? Wk : Wv);
    const float* bias = mat == 0 ? bq : (mat == 1 ? bk : bv);
    const float scale = (mat == 0) ? 0.125f * LOG2E : 1.0f;

    f32x4 acc[2][4];
    gemm_core64(A, W, D_MODEL, m0, n0, 0, D_MODEL, acc);

    const int lane = threadIdx.x & 63, w = threadIdx.x >> 6;
    const int l15 = lane & 15, lg = lane >> 4;
    const int wr = (w >> 1) * 32, wc = (w & 1) * 64;

    if (mat == 2) {
        // transposed V: value (s,d) -> Vo[(b*NH+h)*DK*SEQ + d*SEQ + swz64(s,d)]
#pragma unroll
        for (int m = 0; m < 2; ++m)
#pragma unroll
            for (int nn = 0; nn < 4; ++nn) {
                int gn = n0 + wc + nn * 16 + l15;
                float bv2 = bias[gn];
                int h = gn >> 6, d = gn & 63;
                int gm0 = m0 + wr + m * 16 + lg * 4;
                int b = gm0 >> 11, s = gm0 & 2047;
                u64 pk = (u64)f2bf(acc[m][nn][0] + bv2) |
                         ((u64)f2bf(acc[m][nn][1] + bv2) << 16) |
                         ((u64)f2bf(acc[m][nn][2] + bv2) << 32) |
                         ((u64)f2bf(acc[m][nn][3] + bv2) << 48);
                size_t obase = (size_t)(b * NH + h) * DK * SEQ;
                int soff = (s & ~63) + ((((s >> 3) & 7) ^ (d & 7)) << 3) + (s & 7);
                *(u64*)(Vo + obase + (size_t)d * SEQ + soff) = pk;
            }
    } else {
        u16* out = mat == 0 ? Qo : Ko;
#pragma unroll
        for (int m = 0; m < 2; ++m)
#pragma unroll
            for (int nn = 0; nn < 4; ++nn) {
                int gn = n0 + wc + nn * 16 + l15;
                float bv2 = bias[gn];
                int h = gn >> 6, d = gn & 63;
#pragma unroll
                for (int r = 0; r < 4; ++r) {
                    int gm = m0 + wr + m * 16 + lg * 4 + r;
                    int b = gm >> 11, s = gm & 2047;
                    float v = (acc[m][nn][r] + bv2) * scale;
                    out[(((size_t)(b * NH + h)) * SEQ + s) * DK + d] = f2bf(v);
                }
            }
    }
}

// ---------------- flash attention: 256 threads / 4 waves, 32 q-rows per wave ----------------
// Two Q-fragments per wave share every K/V LDS read (2x MFMA per ds_read_b128).
#define KVB 64
__global__ __launch_bounds__(256, 3) void attn_fwd(const u16* __restrict__ Q,
                                                   const u16* __restrict__ Kp,
                                                   const u16* __restrict__ Vg_,
                                                   u16* __restrict__ ctx) {
    __shared__ __align__(16) u16 Kt[2][64 * 64];    // swizzled [kv][d], 8KB each
    __shared__ __align__(16) u16 Vt[2][64 * 64];    // swizzled [d][t], 8KB each
    __shared__ __align__(16) u16 Ps[4][2][16 * 64]; // per-wave, per-frag [q][kv]

    const int tid = threadIdx.x;
    const int lane = tid & 63;
    const int w = tid >> 6;                          // 0..3
    const int l15 = lane & 15;
    const int lg = lane >> 4;
    // XCD grouping: 4 heads per XCD, K/V 2MB L2-resident
    const int f = blockIdx.x + 16 * blockIdx.y;      // grid (16, 32) = 512 blocks
    const int bh = f & 31;
    const int qblk = f >> 5;                         // 0..15
    const int qbase = qblk * 128 + w * 32;
    const u16* Qb = Q + (size_t)bh * SEQ * DK;
    const u16* Kb = Kp + (size_t)bh * SEQ * DK;
    const u16* Vg = Vg_ + (size_t)bh * DK * SEQ;     // [d][s] pre-swizzled

    short8 qfA[2], qfB[2];
#pragma unroll
    for (int hf = 0; hf < 2; ++hf) {
        qfA[hf] = *(const short8*)(Qb + (size_t)(qbase + l15) * DK + hf * 32 + lg * 8);
        qfB[hf] = *(const short8*)(Qb + (size_t)(qbase + 16 + l15) * DK + hf * 32 + lg * 8);
    }

    short8 onesf;
#pragma unroll
    for (int e = 0; e < 8; ++e) onesf[e] = (short)0x3F80;  // bf16 1.0

    f32x4 zero = {0.f, 0.f, 0.f, 0.f};
    f32x4 oA[4], oB[4], s1A = zero, s1B = zero;
#pragma unroll
    for (int db = 0; db < 4; ++db) { oA[db] = zero; oB[db] = zero; }
    float mA = 0.f, mB = 0.f;        // running max (log2 domain), per frag

    u16* PuA = Ps[w][0];
    u16* PuB = Ps[w][1];
    const int psw = l15 & 7;

// 256 threads: two 16B chunks each per 8KB tile
#define STAGE_V(T0, BUF)                                                       \
    {                                                                          \
        _Pragma("unroll") for (int j = 0; j < 2; ++j) {                        \
            int idx = j * 256 + tid;                                           \
            gload_lds16(Vg + (size_t)(idx >> 3) * SEQ + (T0) + (idx & 7) * 8,  \
                        (char*)Vt[BUF] + (j * 256 + w * 64) * 16);             \
        }                                                                      \
    }
#define STAGE_K(T0, BUF)                                                       \
    {                                                                          \
        _Pragma("unroll") for (int j = 0; j < 2; ++j) {                        \
            int idx = j * 256 + tid;                                           \
            int kv = idx >> 3, ck = idx & 7;                                   \
            gload_lds16(Kb + (size_t)((T0) + kv) * DK + ((ck ^ (kv & 7)) * 8), \
                        (char*)Kt[BUF] + (j * 256 + w * 64) * 16);             \
        }                                                                      \
    }
#define KF(BUF, NB, HALF)                                                      \
    (*(const short8*)((const char*)Kt[BUF] + ((NB)*16 + l15) * 128 +           \
                      (((((HALF)*4 + lg)) ^ psw) << 4)))

// softmax for one fragment: defer-max rescale + P = exp2(sc) packed to LDS
#define SOFTMAX(SC, MOWN, OO, SS, PU)                                          \
    {                                                                          \
        float a0 = fmaxf(fmaxf(SC[0][0], SC[0][1]), SC[0][2]);                 \
        float a1 = fmaxf(fmaxf(SC[0][3], SC[1][0]), SC[1][1]);                 \
        float a2 = fmaxf(fmaxf(SC[1][2], SC[1][3]), SC[2][0]);                 \
        float a3 = fmaxf(fmaxf(SC[2][1], SC[2][2]), SC[2][3]);                 \
        float a4 = fmaxf(fmaxf(SC[3][0], SC[3][1]), SC[3][2]);                 \
        float lm = fmaxf(fmaxf(fmaxf(a0, a1), a2),                             \
                         fmaxf(fmaxf(a3, a4), SC[3][3]));                      \
        if (__any(lm > 8.f)) {                                                 \
            float rv = fmaxf(lm, __shfl_xor(lm, 16));                          \
            rv = fmaxf(rv, __shfl_xor(rv, 32));                                \
            float rvp = fmaxf(rv, 0.f);                                        \
            float fac = fexp2(-rvp);                                           \
            MOWN += rvp;                                                       \
            _Pragma("unroll") for (int nb = 0; nb < 4; ++nb)                   \
                _Pragma("unroll") for (int r = 0; r < 4; ++r)                  \
                    SC[nb][r] -= rvp;                                          \
            _Pragma("unroll") for (int r = 0; r < 4; ++r) {                    \
                float fr = __shfl(fac, lg * 4 + r);                            \
                SS[r] *= fr;                                                   \
                _Pragma("unroll") for (int db = 0; db < 4; ++db)               \
                    OO[db][r] *= fr;                                           \
            }                                                                  \
        }                                                                      \
        _Pragma("unroll") for (int nb = 0; nb < 4; ++nb) {                     \
            float p0 = fexp2(SC[nb][0]);                                       \
            float p1 = fexp2(SC[nb][1]);                                       \
            float p2 = fexp2(SC[nb][2]);                                       \
            float p3 = fexp2(SC[nb][3]);                                       \
            u32 pk01 = __builtin_amdgcn_perm(__builtin_bit_cast(u32, p1),      \
                                             __builtin_bit_cast(u32, p0),      \
                                             0x07060302u);                     \
            u32 pk23 = __builtin_amdgcn_perm(__builtin_bit_cast(u32, p3),      \
                                             __builtin_bit_cast(u32, p2),      \
                                             0x07060302u);                     \
            int ck = (nb * 2 + (lg >> 1)) ^ psw;                               \
            u64* dst = (u64*)(PU + l15 * 64 + ck * 8 + (lg & 1) * 4);          \
            *dst = (u64)pk01 | ((u64)pk23 << 32);                              \
        }                                                                      \
    }

// one KV tile: both fragments share every K/V LDS read
#define ATTN_TILE(BUF)                                                         \
    {                                                                          \
        f32x4 seedA = {-mA, -mA, -mA, -mA};                                    \
        f32x4 seedB = {-mB, -mB, -mB, -mB};                                    \
        f32x4 scA[4], scB[4];                                                  \
        __builtin_amdgcn_s_setprio(1);                                         \
        _Pragma("unroll") for (int nb = 0; nb < 4; ++nb) {                     \
            short8 k0 = KF(BUF, nb, 0);                                        \
            short8 k1 = KF(BUF, nb, 1);                                        \
            scA[nb] = __builtin_amdgcn_mfma_f32_16x16x32_bf16(                 \
                k0, qfA[0], seedA, 0, 0, 0);                                   \
            scA[nb] = __builtin_amdgcn_mfma_f32_16x16x32_bf16(                 \
                k1, qfA[1], scA[nb], 0, 0, 0);                                 \
            scB[nb] = __builtin_amdgcn_mfma_f32_16x16x32_bf16(                 \
                k0, qfB[0], seedB, 0, 0, 0);                                   \
            scB[nb] = __builtin_amdgcn_mfma_f32_16x16x32_bf16(                 \
                k1, qfB[1], scB[nb], 0, 0, 0);                                 \
        }                                                                      \
        __builtin_amdgcn_s_setprio(0);                                         \
        SOFTMAX(scA, mA, oA, s1A, PuA)                                         \
        SOFTMAX(scB, mB, oB, s1B, PuB)                                         \
        short8 paA[2], paB[2];                                                 \
        _Pragma("unroll") for (int ts = 0; ts < 2; ++ts) {                     \
            paA[ts] = *(const short8*)(PuA + l15 * 64 +                        \
                                       (((ts * 4 + lg) ^ psw) * 8));           \
            paB[ts] = *(const short8*)(PuB + l15 * 64 +                        \
                                       (((ts * 4 + lg) ^ psw) * 8));           \
        }                                                                      \
        __builtin_amdgcn_s_setprio(1);                                         \
        _Pragma("unroll") for (int db = 0; db < 4; ++db) {                     \
            const int d = db * 16 + l15;                                       \
            _Pragma("unroll") for (int ts = 0; ts < 2; ++ts) {                 \
                short8 vb = *(const short8*)((const char*)Vt[BUF] + d * 128 +  \
                                             (((ts * 4 + lg) ^ psw) << 4));    \
                oA[db] = __builtin_amdgcn_mfma_f32_16x16x32_bf16(              \
                    paA[ts], vb, oA[db], 0, 0, 0);                             \
                oB[db] = __builtin_amdgcn_mfma_f32_16x16x32_bf16(              \
                    paB[ts], vb, oB[db], 0, 0, 0);                             \
            }                                                                  \
        }                                                                      \
        s1A = __builtin_amdgcn_mfma_f32_16x16x32_bf16(paA[0], onesf, s1A, 0, 0, 0); \
        s1A = __builtin_amdgcn_mfma_f32_16x16x32_bf16(paA[1], onesf, s1A, 0, 0, 0); \
        s1B = __builtin_amdgcn_mfma_f32_16x16x32_bf16(paB[0], onesf, s1B, 0, 0, 0); \
        s1B = __builtin_amdgcn_mfma_f32_16x16x32_bf16(paB[1], onesf, s1B, 0, 0, 0); \
        __builtin_amdgcn_s_setprio(0);                                         \
    }

    STAGE_K(0, 0);
    STAGE_V(0, 0);

    for (int t0 = 0; t0 < SEQ; t0 += 2 * KVB) {   // 16 iterations, static buf ids
        __syncthreads();                          // buf0@t0 loaded; buf1 readers done
        STAGE_K(t0 + KVB, 1);
        STAGE_V(t0 + KVB, 1);
        ATTN_TILE(0);
        __syncthreads();                          // buf1 loaded; buf0 readers done
        if (t0 + 2 * KVB < SEQ) {
            STAGE_K(t0 + 2 * KVB, 0);
            STAGE_V(t0 + 2 * KVB, 0);
        }
        ATTN_TILE(1);
    }

    const int b = bh >> 4, h = bh & 15;
#pragma unroll
    for (int r = 0; r < 4; ++r) {
        float invA = 1.0f / s1A[r];
        float invB = 1.0f / s1B[r];
        int srowA = qbase + lg * 4 + r;
        int srowB = qbase + 16 + lg * 4 + r;
        size_t rowA = ((size_t)(b * SEQ + srowA)) * D_MODEL + h * DK;
        size_t rowB = ((size_t)(b * SEQ + srowB)) * D_MODEL + h * DK;
#pragma unroll
        for (int db = 0; db < 4; ++db) {
            ctx[rowA + db * 16 + l15] = f2bf(oA[db][r] * invA);
            ctx[rowB + db * 16 + l15] = f2bf(oB[db][r] * invB);
        }
    }
#undef STAGE_V
#undef STAGE_K
#undef KF
#undef SOFTMAX
#undef ATTN_TILE
}

// ---------------- fused residual + LayerNorm; X fp32 or bf16, bf16 Y / optional bf16 Y2 ----------------
template <bool XBF>
__global__ __launch_bounds__(256) void ln_res(const void* __restrict__ Xv,
                                              const u16* __restrict__ Y,
                                              const u16* __restrict__ Y2,
                                              const float* __restrict__ gamma,
                                              const float* __restrict__ beta,
                                              float* __restrict__ outf,
                                              u16* __restrict__ outb) {
    __shared__ float red[8];
    const int row = blockIdx.x, t = threadIdx.x;
    const size_t off = (size_t)row * D_MODEL + t * 4;
    float x0, x1_, x2, x3;
    if (XBF) {
        ushort4 xv = *(const ushort4*)((const u16*)Xv + off);
        x0 = bf2f(xv.x); x1_ = bf2f(xv.y); x2 = bf2f(xv.z); x3 = bf2f(xv.w);
    } else {
        float4 xv = *(const float4*)((const float*)Xv + off);
        x0 = xv.x; x1_ = xv.y; x2 = xv.z; x3 = xv.w;
    }
    ushort4 yv = *(const ushort4*)(Y + off);
    float sx = x0 + bf2f(yv.x), sy = x1_ + bf2f(yv.y);
    float sz = x2 + bf2f(yv.z), sw = x3 + bf2f(yv.w);
    if (Y2) {
        ushort4 y2 = *(const ushort4*)(Y2 + off);
        sx += bf2f(y2.x); sy += bf2f(y2.y); sz += bf2f(y2.z); sw += bf2f(y2.w);
    }
    float ps = sx + sy + sz + sw;
#pragma unroll
    for (int o2 = 32; o2; o2 >>= 1) ps += __shfl_xor(ps, o2);
    if ((t & 63) == 0) red[t >> 6] = ps;
    __syncthreads();
    float mu = (red[0] + red[1] + red[2] + red[3]) * (1.0f / D_MODEL);
    float d0 = sx - mu, d1 = sy - mu, d2 = sz - mu, d3 = sw - mu;
    float p2 = d0 * d0 + d1 * d1 + d2 * d2 + d3 * d3;
#pragma unroll
    for (int o2 = 32; o2; o2 >>= 1) p2 += __shfl_xor(p2, o2);
    if ((t & 63) == 0) red[4 + (t >> 6)] = p2;
    __syncthreads();
    float var = (red[4] + red[5] + red[6] + red[7]) * (1.0f / D_MODEL);
    float rstd = rsqrtf(var + 1e-5f);
    float4 gv = *(const float4*)(gamma + t * 4);
    float4 bv = *(const float4*)(beta + t * 4);
    float r0 = d0 * rstd * gv.x + bv.x;
    float r1 = d1 * rstd * gv.y + bv.y;
    float r2 = d2 * rstd * gv.z + bv.z;
    float r3 = d3 * rstd * gv.w + bv.w;
    if (outf) {
        float4 res; res.x = r0; res.y = r1; res.z = r2; res.w = r3;
        *(float4*)(outf + off) = res;
    }
    if (outb) {
        outb[off + 0] = f2bf(r0);
        outb[off + 1] = f2bf(r1);
        outb[off + 2] = f2bf(r2);
        outb[off + 3] = f2bf(r3);
    }
}

extern "C" void kernel_launch(void* const* d_in, const int* in_sizes, int n_in,
                              void* d_out, int out_size, void* d_ws, size_t ws_size,
                              hipStream_t stream) {
    (void)in_sizes; (void)n_in; (void)out_size; (void)ws_size;
    const float* x  = (const float*)d_in[0];
    const float* Wq = (const float*)d_in[1];
    const float* bq = (const float*)d_in[2];
    const float* Wk = (const float*)d_in[3];
    const float* bk = (const float*)d_in[4];
    const float* Wv = (const float*)d_in[5];
    const float* bv = (const float*)d_in[6];
    const float* Wo = (const float*)d_in[7];
    const float* bo = (const float*)d_in[8];
    const float* W1 = (const float*)d_in[9];
    const float* b1 = (const float*)d_in[10];
    const float* W2 = (const float*)d_in[11];
    const float* b2 = (const float*)d_in[12];
    const float* g1 = (const float*)d_in[13];
    const float* be1 = (const float*)d_in[14];
    const float* g2 = (const float*)d_in[15];
    const float* be2 = (const float*)d_in[16];

    char* ws = (char*)d_ws;                         // 96 MB total, overlapped
    u16* xb   = (u16*)(ws);                         // 8 MB : x bf16, then ctx
    u16* Qb   = (u16*)(ws + ((size_t)8 << 20));     // 8 MB : Q
    u16* Kb   = (u16*)(ws + ((size_t)16 << 20));    // 8 MB : K
    u16* x1b  = (u16*)(ws + ((size_t)24 << 20));    // 8 MB : x1 (bf16, step 5+)
    u16* W1b  = (u16*)(ws + ((size_t)32 << 20));    // 8 MB : W1 bf16
    u16* W2b  = (u16*)(ws + ((size_t)40 << 20));    // 8 MB : W2 bf16
    u16* Fs   = (u16*)(ws + ((size_t)48 << 20));    // 8 MB : V^T, then attn_out/ffA
    u16* Fs2  = (u16*)(ws + ((size_t)56 << 20));    // 8 MB : attn_outB/ffB
    u16* hb   = (u16*)(ws + ((size_t)64 << 20));    // 32 MB : Wq-o bf16 (4MB), then h
    u16* Wqb = hb;
    u16* Wkb = hb + (1u << 20);
    u16* Wvb = hb + (2u << 20);
    u16* Wob = hb + (3u << 20);
    u16* Vtg = Fs;                                  // V^T (dead before Wo writes Fs)
    u16* ctxb = xb;

    // 1. convert x + all 6 weight matrices to bf16 in one launch
    cvt_all<<<dim3(16384), 256, 0, stream>>>(x, Wq, Wk, Wv, Wo, W1, W2,
                                             xb, Wqb, Wkb, Wvb, Wob, W1b, W2b);

    // 2. fused QKV projections on k64 core (m-stripe XCD grouping)
    gemm_qkv<<<dim3(1536), 256, 0, stream>>>(xb, Wqb, Wkb, Wvb, bq, bk, bv,
                                             Qb, Kb, Vtg);

    // 3. attention -> ctx (256-thread blocks, 4 waves x 32 q-rows, KVB=64)
    attn_fwd<<<dim3(SEQ / 128, 32), 256, 0, stream>>>(Qb, Kb, Vtg, ctxb);

    // 4. output projection -> Fs + Fs2 (bf16 split-K x2), m-stripe XCD grouping
    gemm_k64<<<dim3(1024), 256, 0, stream>>>(ctxb, Wob, bo, Fs, Fs2,
                                             NTOK, D_MODEL, D_MODEL, 2);

    // 5. x1 = LN(x + attn_outA + attn_outB) -> bf16 only
    ln_res<false><<<dim3(NTOK), 256, 0, stream>>>(x, Fs, Fs2, g1, be1,
                                                  nullptr, x1b);

    // 6. h = relu(x1 @ W1^T + b1) on k64 core, 2048 blocks
    gemm_k64_relu<<<dim3(2048), 256, 0, stream>>>(x1b, W1b, b1, hb,
                                                  NTOK, DFF, D_MODEL);

    // 7. ff = h @ W2^T + b2 -> Fs + Fs2 (bf16 split-K x2), m-stripe XCD grouping
    gemm_k64<<<dim3(1024), 256, 0, stream>>>(hb, W2b, b2, Fs, Fs2,
                                             NTOK, D_MODEL, DFF, 2);

    // 8. out = LN(x1 + ffA + ffB)
    ln_res<true><<<dim3(NTOK), 256, 0, stream>>>(x1b, Fs, Fs2, g2, be2,
                                                 (float*)d_out, nullptr);
}

// Round 20
// 221.029 us; speedup vs baseline: 1.0190x; 1.0190x over previous
//
#include <hip/hip_runtime.h>

typedef unsigned short u16;
typedef unsigned int u32;
typedef unsigned long long u64;
typedef __attribute__((ext_vector_type(8))) short short8;
typedef __attribute__((ext_vector_type(4))) float f32x4;

#define D_MODEL 1024
#define SEQ 2048
#define NH 16
#define DK 64
#define DFF 4096
#define NTOK 4096
#define LOG2E 1.44269504f

__device__ __forceinline__ u16 f2bf(float f) {
    unsigned x = __builtin_bit_cast(unsigned, f);
    x = x + 0x7fffu + ((x >> 16) & 1u);
    return (u16)(x >> 16);
}

__device__ __forceinline__ float bf2f(u16 v) {
    return __builtin_bit_cast(float, (u32)v << 16);
}

// bare v_exp_f32 (inputs <= 8 after defer-max; flush-to-zero ok)
__device__ __forceinline__ float fexp2(float x) {
    float r;
    asm("v_exp_f32 %0, %1" : "=v"(r) : "v"(x));
    return r;
}

__device__ __forceinline__ void gload_lds16(const void* g, void* l) {
    __builtin_amdgcn_global_load_lds(
        (__attribute__((address_space(1))) void*)g,
        (__attribute__((address_space(3))) void*)l, 16, 0, 0);
}

// ---------------- fp32 -> bf16 convert: all 7 tensors in one launch ----------------
__device__ __forceinline__ void cvt_body(const float* __restrict__ in,
                                         u16* __restrict__ out, int blk) {
    size_t i = ((size_t)blk * 256 + threadIdx.x) * 4;
    float4 v = *(const float4*)(in + i);
    out[i + 0] = f2bf(v.x);
    out[i + 1] = f2bf(v.y);
    out[i + 2] = f2bf(v.z);
    out[i + 3] = f2bf(v.w);
}

__global__ __launch_bounds__(256) void cvt_all(
    const float* __restrict__ sx, const float* __restrict__ s0,
    const float* __restrict__ s1, const float* __restrict__ s2,
    const float* __restrict__ s3, const float* __restrict__ s4,
    const float* __restrict__ s5, u16* __restrict__ dx, u16* __restrict__ d0,
    u16* __restrict__ d1, u16* __restrict__ d2, u16* __restrict__ d3,
    u16* __restrict__ d4, u16* __restrict__ d5) {
    int f = blockIdx.x;
    if (f < 4096) {
        cvt_body(sx, dx, f);
    } else if (f < 8192) {
        int which = (f - 4096) >> 10, blk = (f - 4096) & 1023;
        const float* s = which == 0 ? s0 : which == 1 ? s1 : which == 2 ? s2 : s3;
        u16* d = which == 0 ? d0 : which == 1 ? d1 : which == 2 ? d2 : d3;
        cvt_body(s, d, blk);
    } else if (f < 12288) {
        cvt_body(s4, d4, f - 8192);
    } else {
        cvt_body(s5, d5, f - 12288);
    }
}

// ---------------- shared 64x128 tile, BK=64 GEMM core (XOR-swizzled LDS) ----------------
// Single-buffered (24KB LDS -> 6 blocks/CU); occupancy provides the latency hiding.
__device__ __forceinline__ void gemm_core64(const u16* __restrict__ A,
                                            const u16* __restrict__ W, int K,
                                            int m0, int n0, int kbase, int kl,
                                            f32x4 (&acc)[2][4]) {
    __shared__ short8 As[64][8];
    __shared__ short8 Bs[128][8];
    const int tid = threadIdx.x;
    const int lane = tid & 63, w = tid >> 6;
    const int l15 = lane & 15, lg = lane >> 4;
    const int wr = (w >> 1) * 32, wc = (w & 1) * 64;
    const int psw = l15 & 7;

#pragma unroll
    for (int i = 0; i < 2; ++i)
#pragma unroll
        for (int jj = 0; jj < 4; ++jj) acc[i][jj] = (f32x4){0.f, 0.f, 0.f, 0.f};

    for (int k0 = kbase; k0 < kbase + kl; k0 += 64) {
        __syncthreads();
#pragma unroll
        for (int jj = 0; jj < 2; ++jj) {
            int idx = jj * 256 + tid;
            int r = idx >> 3, ck = idx & 7;
            gload_lds16(A + (size_t)(m0 + r) * K + k0 + ((ck ^ (r & 7)) * 8),
                        (char*)As + (jj * 256 + w * 64) * 16);
        }
#pragma unroll
        for (int jj = 0; jj < 4; ++jj) {
            int idx = jj * 256 + tid;
            int r = idx >> 3, ck = idx & 7;
            gload_lds16(W + (size_t)(n0 + r) * K + k0 + ((ck ^ (r & 7)) * 8),
                        (char*)Bs + (jj * 256 + w * 64) * 16);
        }
        __syncthreads();

#pragma unroll
        for (int kk = 0; kk < 2; ++kk) {
            short8 af[2], bf[4];
#pragma unroll
            for (int m = 0; m < 2; ++m)
                af[m] = As[wr + m * 16 + l15][(kk * 4 + lg) ^ psw];
#pragma unroll
            for (int nn = 0; nn < 4; ++nn)
                bf[nn] = Bs[wc + nn * 16 + l15][(kk * 4 + lg) ^ psw];
#pragma unroll
            for (int m = 0; m < 2; ++m)
#pragma unroll
                for (int nn = 0; nn < 4; ++nn)
                    acc[m][nn] = __builtin_amdgcn_mfma_f32_16x16x32_bf16(
                        af[m], bf[nn], acc[m][nn], 0, 0, 0);
        }
    }
}

// ---------------- k64 GEMM, bf16 out, optional split-K (Wo/W2, N=1024) ----------------
__global__ __launch_bounds__(256) void gemm_k64(
    const u16* __restrict__ A, const u16* __restrict__ W,
    const float* __restrict__ bias, u16* __restrict__ outb,
    u16* __restrict__ outb2, int M, int N, int K, int KZ) {
    const int f = blockIdx.x;
    const int xcd = f & 7, j = f >> 3;
    const int mi = j & 7, n = (j >> 3) & 7, kz = j >> 6;
    const int m0 = (xcd * 8 + mi) * 64, n0 = n * 128;
    const int kl = K / KZ, kbase = kz * kl;
    u16* out = kz ? outb2 : outb;

    f32x4 acc[2][4];
    gemm_core64(A, W, K, m0, n0, kbase, kl, acc);

    const int lane = threadIdx.x & 63, w = threadIdx.x >> 6;
    const int l15 = lane & 15, lg = lane >> 4;
    const int wr = (w >> 1) * 32, wc = (w & 1) * 64;
#pragma unroll
    for (int m = 0; m < 2; ++m)
#pragma unroll
        for (int nn = 0; nn < 4; ++nn) {
            int gn = n0 + wc + nn * 16 + l15;
            float bv = (kz == 0) ? bias[gn] : 0.f;
#pragma unroll
            for (int r = 0; r < 4; ++r) {
                int gm = m0 + wr + m * 16 + lg * 4 + r;
                out[(size_t)gm * N + gn] = f2bf(acc[m][nn][r] + bv);
            }
        }
}

// ---------------- k64 GEMM, relu bf16 out (W1, N=4096): 2048 blocks ----------------
__global__ __launch_bounds__(256) void gemm_k64_relu(
    const u16* __restrict__ A, const u16* __restrict__ W,
    const float* __restrict__ bias, u16* __restrict__ outb, int M, int N,
    int K) {
    const int f = blockIdx.x;
    const int xcd = f & 7, j = f >> 3;          // j 0..255
    const int mi = j & 7, n = j >> 3;           // n 0..31
    const int m0 = (xcd * 8 + mi) * 64, n0 = n * 128;

    f32x4 acc[2][4];
    gemm_core64(A, W, K, m0, n0, 0, K, acc);

    const int lane = threadIdx.x & 63, w = threadIdx.x >> 6;
    const int l15 = lane & 15, lg = lane >> 4;
    const int wr = (w >> 1) * 32, wc = (w & 1) * 64;
#pragma unroll
    for (int m = 0; m < 2; ++m)
#pragma unroll
        for (int nn = 0; nn < 4; ++nn) {
            int gn = n0 + wc + nn * 16 + l15;
            float bv = bias[gn];
#pragma unroll
            for (int r = 0; r < 4; ++r) {
                int gm = m0 + wr + m * 16 + lg * 4 + r;
                outb[(size_t)gm * N + gn] = f2bf(fmaxf(acc[m][nn][r] + bv, 0.f));
            }
        }
}

// ---------------- fused QKV on k64 core: 1536 blocks, m-stripe per XCD ----------------
// Q/K in [B,H,S,dk] (Q pre-scaled by 1/8*log2e); V transposed+swizzled to [B,H,dk,S].
__global__ __launch_bounds__(256) void gemm_qkv(
    const u16* __restrict__ A, const u16* __restrict__ Wq,
    const u16* __restrict__ Wk, const u16* __restrict__ Wv,
    const float* __restrict__ bq, const float* __restrict__ bk,
    const float* __restrict__ bv, u16* __restrict__ Qo, u16* __restrict__ Ko,
    u16* __restrict__ Vo) {
    const int f = blockIdx.x;
    const int xcd = f & 7, j = f >> 3;          // j 0..191
    const int mi = j & 7, q = j >> 3;           // q 0..23
    const int mat = q >> 3;
    const int m0 = (xcd * 8 + mi) * 64, n0 = (q & 7) * 128;
    const u16* W = mat == 0 ? Wq : (mat == 1 ? Wk : Wv);
    const float* bias = mat == 0 ? bq : (mat == 1 ? bk : bv);
    const float scale = (mat == 0) ? 0.125f * LOG2E : 1.0f;

    f32x4 acc[2][4];
    gemm_core64(A, W, D_MODEL, m0, n0, 0, D_MODEL, acc);

    const int lane = threadIdx.x & 63, w = threadIdx.x >> 6;
    const int l15 = lane & 15, lg = lane >> 4;
    const int wr = (w >> 1) * 32, wc = (w & 1) * 64;

    if (mat == 2) {
        // transposed V: value (s,d) -> Vo[(b*NH+h)*DK*SEQ + d*SEQ + swz64(s,d)]
#pragma unroll
        for (int m = 0; m < 2; ++m)
#pragma unroll
            for (int nn = 0; nn < 4; ++nn) {
                int gn = n0 + wc + nn * 16 + l15;
                float bv2 = bias[gn];
                int h = gn >> 6, d = gn & 63;
                int gm0 = m0 + wr + m * 16 + lg * 4;
                int b = gm0 >> 11, s = gm0 & 2047;
                u64 pk = (u64)f2bf(acc[m][nn][0] + bv2) |
                         ((u64)f2bf(acc[m][nn][1] + bv2) << 16) |
                         ((u64)f2bf(acc[m][nn][2] + bv2) << 32) |
                         ((u64)f2bf(acc[m][nn][3] + bv2) << 48);
                size_t obase = (size_t)(b * NH + h) * DK * SEQ;
                int soff = (s & ~63) + ((((s >> 3) & 7) ^ (d & 7)) << 3) + (s & 7);
                *(u64*)(Vo + obase + (size_t)d * SEQ + soff) = pk;
            }
    } else {
        u16* out = mat == 0 ? Qo : Ko;
#pragma unroll
        for (int m = 0; m < 2; ++m)
#pragma unroll
            for (int nn = 0; nn < 4; ++nn) {
                int gn = n0 + wc + nn * 16 + l15;
                float bv2 = bias[gn];
                int h = gn >> 6, d = gn & 63;
#pragma unroll
                for (int r = 0; r < 4; ++r) {
                    int gm = m0 + wr + m * 16 + lg * 4 + r;
                    int b = gm >> 11, s = gm & 2047;
                    float v = (acc[m][nn][r] + bv2) * scale;
                    out[(((size_t)(b * NH + h)) * SEQ + s) * DK + d] = f2bf(v);
                }
            }
    }
}

// ---------------- flash attention: 512 threads, KVB=64 dbuf, P stride 64 ----------------
#define KVB 64
__global__ __launch_bounds__(512) void attn_fwd(const u16* __restrict__ Q,
                                                const u16* __restrict__ Kp,
                                                const u16* __restrict__ Vg_,
                                                u16* __restrict__ ctx) {
    __shared__ __align__(16) u16 Kt[2][64 * 64];    // swizzled [kv][d], 8KB each
    __shared__ __align__(16) u16 Vt[2][64 * 64];    // swizzled [d][t], 8KB each
    __shared__ __align__(16) u16 Ps[8][16 * 64];    // per-wave [q][kv], chunk-XOR swizzle

    const int tid = threadIdx.x;
    const int lane = tid & 63;
    const int w = tid >> 6;                          // 0..7
    const int l15 = lane & 15;
    const int lg = lane >> 4;
    // XCD grouping: 4 heads per XCD, K/V 2MB L2-resident
    const int f = blockIdx.x + 16 * blockIdx.y;      // grid (16, 32) = 512 blocks
    const int bh = f & 31;
    const int qblk = f >> 5;                         // 0..15
    const int qbase = qblk * 128 + w * 16;
    const u16* Qb = Q + (size_t)bh * SEQ * DK;
    const u16* Kb = Kp + (size_t)bh * SEQ * DK;
    const u16* Vg = Vg_ + (size_t)bh * DK * SEQ;     // [d][s] pre-swizzled

    short8 qf[2];
#pragma unroll
    for (int hf = 0; hf < 2; ++hf)
        qf[hf] = *(const short8*)(Qb + (size_t)(qbase + l15) * DK + hf * 32 + lg * 8);

    short8 onesf;
#pragma unroll
    for (int e = 0; e < 8; ++e) onesf[e] = (short)0x3F80;  // bf16 1.0

    f32x4 zero = {0.f, 0.f, 0.f, 0.f};
    f32x4 o[4], o1 = zero;
#pragma unroll
    for (int db = 0; db < 4; ++db) o[db] = zero;
    float m_own = 0.f;               // running max (log2 domain) for q = l15

    u16* Pu = Ps[w];
    const int psw = l15 & 7;

// 512 threads: one 16B chunk each per 8KB tile
#define STAGE_V(T0, BUF)                                                       \
    {                                                                          \
        gload_lds16(Vg + (size_t)(tid >> 3) * SEQ + (T0) + (tid & 7) * 8,      \
                    (char*)Vt[BUF] + (w * 64) * 16);                           \
    }
#define STAGE_K(T0, BUF)                                                       \
    {                                                                          \
        int kv = tid >> 3, ck = tid & 7;                                       \
        gload_lds16(Kb + (size_t)((T0) + kv) * DK + ((ck ^ (kv & 7)) * 8),     \
                    (char*)Kt[BUF] + (w * 64) * 16);                           \
    }
#define KF(BUF, NB, HALF)                                                      \
    (*(const short8*)((const char*)Kt[BUF] + ((NB)*16 + l15) * 128 +           \
                      (((((HALF)*4 + lg)) ^ psw) << 4)))

#define ATTN_TILE(BUF)                                                         \
    {                                                                          \
        f32x4 seed = {-m_own, -m_own, -m_own, -m_own};                         \
        f32x4 sc[4];                                                           \
        __builtin_amdgcn_s_setprio(1);                                         \
        _Pragma("unroll") for (int nb = 0; nb < 4; ++nb) {                     \
            sc[nb] = __builtin_amdgcn_mfma_f32_16x16x32_bf16(                  \
                KF(BUF, nb, 0), qf[0], seed, 0, 0, 0);                         \
            sc[nb] = __builtin_amdgcn_mfma_f32_16x16x32_bf16(                  \
                KF(BUF, nb, 1), qf[1], sc[nb], 0, 0, 0);                       \
        }                                                                      \
        __builtin_amdgcn_s_setprio(0);                                         \
        float a0 = fmaxf(fmaxf(sc[0][0], sc[0][1]), sc[0][2]);                 \
        float a1 = fmaxf(fmaxf(sc[0][3], sc[1][0]), sc[1][1]);                 \
        float a2 = fmaxf(fmaxf(sc[1][2], sc[1][3]), sc[2][0]);                 \
        float a3 = fmaxf(fmaxf(sc[2][1], sc[2][2]), sc[2][3]);                 \
        float a4 = fmaxf(fmaxf(sc[3][0], sc[3][1]), sc[3][2]);                 \
        float lm = fmaxf(fmaxf(fmaxf(a0, a1), a2),                             \
                         fmaxf(fmaxf(a3, a4), sc[3][3]));                      \
        if (__any(lm > 8.f)) {                                                 \
            float rv = fmaxf(lm, __shfl_xor(lm, 16));                          \
            rv = fmaxf(rv, __shfl_xor(rv, 32));                                \
            float rvp = fmaxf(rv, 0.f);                                        \
            float fac = fexp2(-rvp);                                           \
            m_own += rvp;                                                      \
            _Pragma("unroll") for (int nb = 0; nb < 4; ++nb)                   \
                _Pragma("unroll") for (int r = 0; r < 4; ++r)                  \
                    sc[nb][r] -= rvp;                                          \
            _Pragma("unroll") for (int r = 0; r < 4; ++r) {                    \
                float fr = __shfl(fac, lg * 4 + r);                            \
                o1[r] *= fr;                                                   \
                _Pragma("unroll") for (int db = 0; db < 4; ++db)               \
                    o[db][r] *= fr;                                            \
            }                                                                  \
        }                                                                      \
        _Pragma("unroll") for (int nb = 0; nb < 4; ++nb) {                     \
            float p0 = fexp2(sc[nb][0]);                                       \
            float p1 = fexp2(sc[nb][1]);                                       \
            float p2 = fexp2(sc[nb][2]);                                       \
            float p3 = fexp2(sc[nb][3]);                                       \
            u32 pk01 = __builtin_amdgcn_perm(__builtin_bit_cast(u32, p1),      \
                                             __builtin_bit_cast(u32, p0),      \
                                             0x07060302u);                     \
            u32 pk23 = __builtin_amdgcn_perm(__builtin_bit_cast(u32, p3),      \
                                             __builtin_bit_cast(u32, p2),      \
                                             0x07060302u);                     \
            int ck = (nb * 2 + (lg >> 1)) ^ psw;                               \
            u64* dst = (u64*)(Pu + l15 * 64 + ck * 8 + (lg & 1) * 4);          \
            *dst = (u64)pk01 | ((u64)pk23 << 32);                              \
        }                                                                      \
        short8 pa[2];                                                          \
        _Pragma("unroll") for (int ts = 0; ts < 2; ++ts)                       \
            pa[ts] = *(const short8*)(Pu + l15 * 64 + (((ts * 4 + lg) ^ psw) * 8)); \
        __builtin_amdgcn_s_setprio(1);                                         \
        _Pragma("unroll") for (int db = 0; db < 4; ++db) {                     \
            const int d = db * 16 + l15;                                       \
            _Pragma("unroll") for (int ts = 0; ts < 2; ++ts) {                 \
                short8 vb = *(const short8*)((const char*)Vt[BUF] + d * 128 +  \
                                             (((ts * 4 + lg) ^ psw) << 4));    \
                o[db] = __builtin_amdgcn_mfma_f32_16x16x32_bf16(               \
                    pa[ts], vb, o[db], 0, 0, 0);                               \
            }                                                                  \
        }                                                                      \
        o1 = __builtin_amdgcn_mfma_f32_16x16x32_bf16(pa[0], onesf, o1, 0, 0, 0); \
        o1 = __builtin_amdgcn_mfma_f32_16x16x32_bf16(pa[1], onesf, o1, 0, 0, 0); \
        __builtin_amdgcn_s_setprio(0);                                         \
    }

    STAGE_K(0, 0);
    STAGE_V(0, 0);

    for (int t0 = 0; t0 < SEQ; t0 += 2 * KVB) {   // 16 iterations, static buf ids
        __syncthreads();                          // buf0@t0 loaded; buf1 readers done
        STAGE_K(t0 + KVB, 1);
        STAGE_V(t0 + KVB, 1);
        ATTN_TILE(0);
        __syncthreads();                          // buf1 loaded; buf0 readers done
        if (t0 + 2 * KVB < SEQ) {
            STAGE_K(t0 + 2 * KVB, 0);
            STAGE_V(t0 + 2 * KVB, 0);
        }
        ATTN_TILE(1);
    }

    const int b = bh >> 4, h = bh & 15;
#pragma unroll
    for (int r = 0; r < 4; ++r) {
        float inv = 1.0f / o1[r];
        int srow = qbase + lg * 4 + r;
        size_t rowoff = ((size_t)(b * SEQ + srow)) * D_MODEL + h * DK;
#pragma unroll
        for (int db = 0; db < 4; ++db)
            ctx[rowoff + db * 16 + l15] = f2bf(o[db][r] * inv);
    }
#undef STAGE_V
#undef STAGE_K
#undef KF
#undef ATTN_TILE
}

// ---------------- fused residual + LayerNorm; X fp32 or bf16, bf16 Y / optional bf16 Y2 ----------------
template <bool XBF>
__global__ __launch_bounds__(256) void ln_res(const void* __restrict__ Xv,
                                              const u16* __restrict__ Y,
                                              const u16* __restrict__ Y2,
                                              const float* __restrict__ gamma,
                                              const float* __restrict__ beta,
                                              float* __restrict__ outf,
                                              u16* __restrict__ outb) {
    __shared__ float red[8];
    const int row = blockIdx.x, t = threadIdx.x;
    const size_t off = (size_t)row * D_MODEL + t * 4;
    float x0, x1_, x2, x3;
    if (XBF) {
        ushort4 xv = *(const ushort4*)((const u16*)Xv + off);
        x0 = bf2f(xv.x); x1_ = bf2f(xv.y); x2 = bf2f(xv.z); x3 = bf2f(xv.w);
    } else {
        float4 xv = *(const float4*)((const float*)Xv + off);
        x0 = xv.x; x1_ = xv.y; x2 = xv.z; x3 = xv.w;
    }
    ushort4 yv = *(const ushort4*)(Y + off);
    float sx = x0 + bf2f(yv.x), sy = x1_ + bf2f(yv.y);
    float sz = x2 + bf2f(yv.z), sw = x3 + bf2f(yv.w);
    if (Y2) {
        ushort4 y2 = *(const ushort4*)(Y2 + off);
        sx += bf2f(y2.x); sy += bf2f(y2.y); sz += bf2f(y2.z); sw += bf2f(y2.w);
    }
    float ps = sx + sy + sz + sw;
#pragma unroll
    for (int o2 = 32; o2; o2 >>= 1) ps += __shfl_xor(ps, o2);
    if ((t & 63) == 0) red[t >> 6] = ps;
    __syncthreads();
    float mu = (red[0] + red[1] + red[2] + red[3]) * (1.0f / D_MODEL);
    float d0 = sx - mu, d1 = sy - mu, d2 = sz - mu, d3 = sw - mu;
    float p2 = d0 * d0 + d1 * d1 + d2 * d2 + d3 * d3;
#pragma unroll
    for (int o2 = 32; o2; o2 >>= 1) p2 += __shfl_xor(p2, o2);
    if ((t & 63) == 0) red[4 + (t >> 6)] = p2;
    __syncthreads();
    float var = (red[4] + red[5] + red[6] + red[7]) * (1.0f / D_MODEL);
    float rstd = rsqrtf(var + 1e-5f);
    float4 gv = *(const float4*)(gamma + t * 4);
    float4 bv = *(const float4*)(beta + t * 4);
    float r0 = d0 * rstd * gv.x + bv.x;
    float r1 = d1 * rstd * gv.y + bv.y;
    float r2 = d2 * rstd * gv.z + bv.z;
    float r3 = d3 * rstd * gv.w + bv.w;
    if (outf) {
        float4 res; res.x = r0; res.y = r1; res.z = r2; res.w = r3;
        *(float4*)(outf + off) = res;
    }
    if (outb) {
        outb[off + 0] = f2bf(r0);
        outb[off + 1] = f2bf(r1);
        outb[off + 2] = f2bf(r2);
        outb[off + 3] = f2bf(r3);
    }
}

extern "C" void kernel_launch(void* const* d_in, const int* in_sizes, int n_in,
                              void* d_out, int out_size, void* d_ws, size_t ws_size,
                              hipStream_t stream) {
    (void)in_sizes; (void)n_in; (void)out_size; (void)ws_size;
    const float* x  = (const float*)d_in[0];
    const float* Wq = (const float*)d_in[1];
    const float* bq = (const float*)d_in[2];
    const float* Wk = (const float*)d_in[3];
    const float* bk = (const float*)d_in[4];
    const float* Wv = (const float*)d_in[5];
    const float* bv = (const float*)d_in[6];
    const float* Wo = (const float*)d_in[7];
    const float* bo = (const float*)d_in[8];
    const float* W1 = (const float*)d_in[9];
    const float* b1 = (const float*)d_in[10];
    const float* W2 = (const float*)d_in[11];
    const float* b2 = (const float*)d_in[12];
    const float* g1 = (const float*)d_in[13];
    const float* be1 = (const float*)d_in[14];
    const float* g2 = (const float*)d_in[15];
    const float* be2 = (const float*)d_in[16];

    char* ws = (char*)d_ws;                         // 96 MB total, overlapped
    u16* xb   = (u16*)(ws);                         // 8 MB : x bf16, then ctx
    u16* Qb   = (u16*)(ws + ((size_t)8 << 20));     // 8 MB : Q
    u16* Kb   = (u16*)(ws + ((size_t)16 << 20));    // 8 MB : K
    u16* x1b  = (u16*)(ws + ((size_t)24 << 20));    // 8 MB : x1 (bf16, step 5+)
    u16* W1b  = (u16*)(ws + ((size_t)32 << 20));    // 8 MB : W1 bf16
    u16* W2b  = (u16*)(ws + ((size_t)40 << 20));    // 8 MB : W2 bf16
    u16* Fs   = (u16*)(ws + ((size_t)48 << 20));    // 8 MB : V^T, then attn_out/ffA
    u16* Fs2  = (u16*)(ws + ((size_t)56 << 20));    // 8 MB : attn_outB/ffB
    u16* hb   = (u16*)(ws + ((size_t)64 << 20));    // 32 MB : Wq-o bf16 (4MB), then h
    u16* Wqb = hb;
    u16* Wkb = hb + (1u << 20);
    u16* Wvb = hb + (2u << 20);
    u16* Wob = hb + (3u << 20);
    u16* Vtg = Fs;                                  // V^T (dead before Wo writes Fs)
    u16* ctxb = xb;

    // 1. convert x + all 6 weight matrices to bf16 in one launch
    cvt_all<<<dim3(16384), 256, 0, stream>>>(x, Wq, Wk, Wv, Wo, W1, W2,
                                             xb, Wqb, Wkb, Wvb, Wob, W1b, W2b);

    // 2. fused QKV projections on k64 core (m-stripe XCD grouping)
    gemm_qkv<<<dim3(1536), 256, 0, stream>>>(xb, Wqb, Wkb, Wvb, bq, bk, bv,
                                             Qb, Kb, Vtg);

    // 3. attention -> ctx (512-thread blocks, 8 waves x 16 q-rows, KVB=64)
    attn_fwd<<<dim3(SEQ / 128, 32), 512, 0, stream>>>(Qb, Kb, Vtg, ctxb);

    // 4. output projection -> Fs + Fs2 (bf16 split-K x2), m-stripe XCD grouping
    gemm_k64<<<dim3(1024), 256, 0, stream>>>(ctxb, Wob, bo, Fs, Fs2,
                                             NTOK, D_MODEL, D_MODEL, 2);

    // 5. x1 = LN(x + attn_outA + attn_outB) -> bf16 only
    ln_res<false><<<dim3(NTOK), 256, 0, stream>>>(x, Fs, Fs2, g1, be1,
                                                  nullptr, x1b);

    // 6. h = relu(x1 @ W1^T + b1) on k64 core, 2048 blocks
    gemm_k64_relu<<<dim3(2048), 256, 0, stream>>>(x1b, W1b, b1, hb,
                                                  NTOK, DFF, D_MODEL);

    // 7. ff = h @ W2^T + b2 -> Fs + Fs2 (bf16 split-K x2), m-stripe XCD grouping
    gemm_k64<<<dim3(1024), 256, 0, stream>>>(hb, W2b, b2, Fs, Fs2,
                                             NTOK, D_MODEL, DFF, 2);

    // 8. out = LN(x1 + ffA + ffB)
    ln_res<true><<<dim3(NTOK), 256, 0, stream>>>(x1b, Fs, Fs2, g2, be2,
                                                 (float*)d_out, nullptr);
}